// Round 1
// baseline (513.582 us; speedup 1.0000x reference)
//
#include <hip/hip_runtime.h>

#define DIM   768
#define NCLS  1024
#define INST  64
#define MOM   0.8f

__device__ __forceinline__ float wave_allreduce(float v) {
#pragma unroll
    for (int m = 1; m < 64; m <<= 1) v += __shfl_xor(v, m, 64);
    return v;
}

// grid: (NCLS, 3), block: 256.  Block (b, mod) handles rows [b*64, b*64+64) of
// modality `mod`, which by construction all share class label[b*64].
__global__ __launch_bounds__(256) void fused_class_kernel(
    const float* __restrict__ f0, const float* __restrict__ f1, const float* __restrict__ f2,
    const float* __restrict__ c0, const float* __restrict__ c1, const float* __restrict__ c2,
    const int*   __restrict__ label,
    float*       __restrict__ partial)
{
    const int blk = blockIdx.x;
    const int mod = blockIdx.y;
    const float* __restrict__ feat = (mod == 0) ? f0 : (mod == 1) ? f1 : f2;
    const float* __restrict__ cent = (mod == 0) ? c0 : (mod == 1) ? c1 : c2;

    const int tid  = threadIdx.x;
    const int lane = tid & 63;
    const int wave = tid >> 6;

    __shared__ float lds_sum[4][DIM];   // 12 KB: per-wave normalized sums
    __shared__ float lds_red[4];

    const int cls = label[blk * INST];  // all 64 rows share this class

    // Per-lane accumulator of Sum_{rows} x_norm — lane->element map is
    // row-invariant: lane handles float4 chunks {lane, lane+64, lane+128}.
    float4 a0 = make_float4(0.f, 0.f, 0.f, 0.f);
    float4 a1 = make_float4(0.f, 0.f, 0.f, 0.f);
    float4 a2 = make_float4(0.f, 0.f, 0.f, 0.f);

    const float4* base = (const float4*)feat + (size_t)blk * INST * (DIM / 4);

    // wave w handles rows w, w+4, w+8, ... (tight access window across waves)
#pragma unroll 2
    for (int j = 0; j < INST / 4; ++j) {
        const int r = wave + 4 * j;
        const float4* row = base + (size_t)r * (DIM / 4);
        const float4 x = row[lane];
        const float4 y = row[lane + 64];
        const float4 z = row[lane + 128];

        float s = x.x * x.x + x.y * x.y + x.z * x.z + x.w * x.w
                + y.x * y.x + y.y * y.y + y.z * y.z + y.w * y.w
                + z.x * z.x + z.y * z.y + z.z * z.z + z.w * z.w;
        s = wave_allreduce(s);
        const float inv = 1.0f / fmaxf(sqrtf(s), 1e-12f);  // F.normalize eps

        a0.x = fmaf(x.x, inv, a0.x); a0.y = fmaf(x.y, inv, a0.y);
        a0.z = fmaf(x.z, inv, a0.z); a0.w = fmaf(x.w, inv, a0.w);
        a1.x = fmaf(y.x, inv, a1.x); a1.y = fmaf(y.y, inv, a1.y);
        a1.z = fmaf(y.z, inv, a1.z); a1.w = fmaf(y.w, inv, a1.w);
        a2.x = fmaf(z.x, inv, a2.x); a2.y = fmaf(z.y, inv, a2.y);
        a2.z = fmaf(z.z, inv, a2.z); a2.w = fmaf(z.w, inv, a2.w);
    }

    // dump per-wave sums to LDS
    float4* dst = (float4*)lds_sum[wave];
    dst[lane]       = a0;
    dst[lane + 64]  = a1;
    dst[lane + 128] = a2;
    __syncthreads();

    // per-class term: cnt*||c||^2 - 2*c.S   (the +cnt is folded in at the end)
    float t = 0.f;
#pragma unroll
    for (int k = 0; k < DIM / 256; ++k) {  // 3 iterations
        const int d = tid + k * 256;
        const float S = lds_sum[0][d] + lds_sum[1][d] + lds_sum[2][d] + lds_sum[3][d];
        const float c = fmaf(MOM / (float)INST, S,
                             (1.0f - MOM) * cent[(size_t)cls * DIM + d]);
        t = fmaf((float)INST * c, c, t);
        t = fmaf(-2.0f * c, S, t);
    }
    t = wave_allreduce(t);
    if (lane == 0) lds_red[wave] = t;
    __syncthreads();
    if (tid == 0)
        partial[(size_t)mod * NCLS + blk] =
            lds_red[0] + lds_red[1] + lds_red[2] + lds_red[3];
}

// single block, 1024 threads: reduce 3072 partials -> scalar loss
__global__ __launch_bounds__(1024) void reduce_kernel(
    const float* __restrict__ partial, float* __restrict__ out)
{
    __shared__ float lds[16];
    const int tid = threadIdx.x;
    float t = partial[tid] + partial[tid + 1024] + partial[tid + 2048];
    t = wave_allreduce(t);
    if ((tid & 63) == 0) lds[tid >> 6] = t;
    __syncthreads();
    if (tid == 0) {
        float s = 0.f;
#pragma unroll
        for (int i = 0; i < 16; ++i) s += lds[i];
        const float B = (float)(NCLS * INST);
        // + 3*B accounts for Sum ||x_i||^2 = B per modality; ALPHA = 1
        out[0] = (s + 3.0f * B) / (B * (float)DIM);
    }
}

extern "C" void kernel_launch(void* const* d_in, const int* in_sizes, int n_in,
                              void* d_out, int out_size, void* d_ws, size_t ws_size,
                              hipStream_t stream)
{
    const float* f0 = (const float*)d_in[0];  // RGB_feat  [65536,768]
    const float* f1 = (const float*)d_in[1];  // NIR_feat
    const float* f2 = (const float*)d_in[2];  // TIR_feat
    const float* c0 = (const float*)d_in[3];  // RGB_centers [1024,768]
    const float* c1 = (const float*)d_in[4];  // NIR_centers
    const float* c2 = (const float*)d_in[5];  // TIR_centers
    const int*   lb = (const int*)d_in[6];    // label_ [65536]
    // d_in[7] = epoch (unused by the reference output)

    float* partial = (float*)d_ws;            // 3072 floats, fully written

    dim3 grid(NCLS, 3);
    fused_class_kernel<<<grid, 256, 0, stream>>>(f0, f1, f2, c0, c1, c2, lb, partial);
    reduce_kernel<<<1, 1024, 0, stream>>>(partial, (float*)d_out);
}